// Round 23
// baseline (190.192 us; speedup 1.0000x reference)
//
#include <hip/hip_runtime.h>
#include <hip/hip_bf16.h>

typedef unsigned short u16;
typedef unsigned int u32;
typedef __attribute__((ext_vector_type(8))) __bf16 bf16x8;
typedef __attribute__((ext_vector_type(4))) float f32x4;

#define INV_HD  0.03125f
#define INV_SHD 0.17677669529663687f
#define LOG2E   1.4426950408889634f

__device__ __forceinline__ float b2f(u16 u) {
  union { u32 i; float f; } v; v.i = ((u32)u) << 16; return v.f;
}
__device__ __forceinline__ u16 f2b(float f) {
  union { float f; u32 i; } v; v.f = f;
  u32 x = v.i;
  return (u16)((x + 0x7fffu + ((x >> 16) & 1u)) >> 16);
}
__device__ __forceinline__ bf16x8 ld16(const u16* p) {
  return *reinterpret_cast<const bf16x8*>(p);
}
union U8 { bf16x8 v; u16 s[8]; };
__device__ __forceinline__ u32 cvtpk(float a, float b) {
  u32 r;
  asm("v_cvt_pk_bf16_f32 %0, %1, %2" : "=v"(r) : "v"(a), "v"(b));
  return r;
}
// lane^32 / lane^16 sum reduce via permlane swaps (VALU, no LDS latency)
__device__ __forceinline__ float pl32add(float x) {
  union { float f; u32 u; } c; c.f = x;
  auto r = __builtin_amdgcn_permlane32_swap(c.u, c.u, false, false);
  union { u32 u; float f; } a, b; a.u = r[0]; b.u = r[1];
  return a.f + b.f;
}
__device__ __forceinline__ float pl16add(float x) {
#if __has_builtin(__builtin_amdgcn_permlane16_swap)
  union { float f; u32 u; } c; c.f = x;
  auto r = __builtin_amdgcn_permlane16_swap(c.u, c.u, false, false);
  union { u32 u; float f; } a, b; a.u = r[0]; b.u = r[1];
  return a.f + b.f;
#else
  return x + __shfl_xor(x, 16, 64);
#endif
}

// ---------------- fused prep: A-convert + 2 weight transposes + bias expand ----------------
__global__ __launch_bounds__(256) void kPrep(
    const float* __restrict__ xs1, const float* __restrict__ xs2, const float* __restrict__ xq,
    const float* __restrict__ Wqkv, const float* __restrict__ Wproj, const float* __restrict__ tblg,
    u16* __restrict__ Abf, u16* __restrict__ WTq, u16* __restrict__ WTp, u16* __restrict__ BiasC)
{
  const int bx = blockIdx.x, tid = threadIdx.x;
  if (bx < 6144) {
    int t = bx * 256 + tid;
    int row = t >> 5, c8 = (t & 31) * 8;
    int b = row / 6144, r = row - b * 6144;
    const float* src;
    if (r < 4096)      src = xs1 + ((size_t)b * 4096 + r) * 256;
    else if (r < 5120) src = xs2 + ((size_t)b * 1024 + (r - 4096)) * 256;
    else               src = xq  + ((size_t)b * 1024 + (r - 5120)) * 256;
    U8 u;
#pragma unroll
    for (int j = 0; j < 8; ++j) u.s[j] = f2b(src[c8 + j]);
    *reinterpret_cast<bf16x8*>(Abf + (size_t)row * 256 + c8) = u.v;
  } else if (bx < 6912) {
    int i = (bx - 6144) * 256 + tid;       // 196608
    int n = i >> 8, k = i & 255;
    WTq[i] = f2b(Wqkv[(size_t)k * 768 + n]);
  } else if (bx < 7168) {
    int i = (bx - 6912) * 256 + tid;       // 65536
    int n = i >> 8, k = i & 255;
    WTp[i] = f2b(Wproj[(size_t)k * 256 + n]);
  } else {
    int gid = (bx - 7168) * 256 + tid;     // 8192
    int lane = gid & 63, t = gid >> 6;
    int h = t >> 4, qt = (t >> 2) & 3, kt = t & 3;
    int lr = lane & 15, kg = lane >> 4;
    int q = qt * 16 + lr;
    int qi = q >> 3, qj = q & 7;
    ushort4 out;
#pragma unroll
    for (int i = 0; i < 4; ++i) {
      int key = kt * 16 + kg * 4 + i;
      int ki = key >> 3, kj = key & 7;
      int idx = (qi - ki + 7) * 15 + (qj - kj + 7);
      ((u16*)&out)[i] = f2b(tblg[idx * 8 + h] * (INV_SHD * LOG2E));
    }
    *reinterpret_cast<ushort4*>(BiasC + (size_t)(t * 64 + lane) * 4) = out;
  }
}

// ---------------- QKV GEMM: bf16 A [49152,256] @ [256,768], barrier-free ----------------
// 4 m-tiles per wave; LDS staging 9KB/wave (36KB/block): stage 4 nt-iters, flush, repeat.
__global__ __launch_bounds__(256, 2) void kQKV(
    const u16* __restrict__ Abf,
    const u16* __restrict__ WT, const float* __restrict__ bias,
    u16* __restrict__ qk, u16* __restrict__ VT, u16* __restrict__ VST)
{
  __shared__ u16 St[4][4608];   // 9 KB per wave, 36 KB per block
  const int tid = threadIdx.x;
  const int lane = tid & 63, wid = tid >> 6;
  const int lr = lane & 15, kg = lane >> 4;
  const int m0 = blockIdx.x * 256 + wid * 64;
  const int by = blockIdx.y;
  const int m0blk = blockIdx.x * 256;
  const int bb = m0blk / 6144, rloc = m0blk - bb * 6144;
  u16* S = St[wid];

  bf16x8 a[4][8];
#pragma unroll
  for (int mt = 0; mt < 4; ++mt) {
    const u16* asrc = Abf + (size_t)(m0 + mt * 16 + lr) * 256 + kg * 8;
#pragma unroll
    for (int ks = 0; ks < 8; ++ks) a[mt][ks] = ld16(asrc + ks * 32);
  }

  const int n0 = (by < 4) ? by * 128 : 512 + (by - 4) * 128;
  const u16* bcol0 = WT + (size_t)(n0 + lr) * 256 + kg * 8;

  bf16x8 bq[2][8];
#pragma unroll
  for (int ks = 0; ks < 8; ++ks) bq[0][ks] = ld16(bcol0 + ks * 32);   // nt=0

  if (by < 4) {
    const float qsc = (by < 2) ? (INV_SHD * LOG2E) : 1.f;
#pragma unroll
    for (int nt = 0; nt < 8; ++nt) {
      const int cur = nt & 1, nxt = cur ^ 1;
      if (nt + 1 < 8) {
        const u16* bp = bcol0 + (size_t)(nt + 1) * 16 * 256;
#pragma unroll
        for (int ks = 0; ks < 8; ++ks) bq[nxt][ks] = ld16(bp + ks * 32);
      }
      f32x4 acc[4] = {{0.f,0.f,0.f,0.f},{0.f,0.f,0.f,0.f},{0.f,0.f,0.f,0.f},{0.f,0.f,0.f,0.f}};
#pragma unroll
      for (int ks = 0; ks < 8; ++ks) {
#pragma unroll
        for (int mt = 0; mt < 4; ++mt)
          acc[mt] = __builtin_amdgcn_mfma_f32_16x16x32_bf16(a[mt][ks], bq[cur][ks], acc[mt], 0, 0, 0);
      }
      float bv = bias[n0 + nt * 16 + lr];
      const int tc = (nt & 3) * 16;
#pragma unroll
      for (int mt = 0; mt < 4; ++mt)
#pragma unroll
        for (int i = 0; i < 4; ++i)
          S[(mt * 16 + kg * 4 + i) * 72 + tc + lr] = f2b((acc[mt][i] + bv) * qsc);
      if ((nt & 3) == 3) {
        const int cb = (nt - 3) * 16;   // 0 or 64
#pragma unroll
        for (int p = 0; p < 8; ++p) {
          int row = p * 8 + (lane >> 3), col8 = (lane & 7) * 8;
          bf16x8 v = *reinterpret_cast<const bf16x8*>(&S[row * 72 + col8]);
          *reinterpret_cast<bf16x8*>(qk + (size_t)(m0 + row) * 512 + n0 + cb + col8) = v;
        }
      }
    }
  } else {
    const bool isWin = (rloc < 4096);
    u16* Vb = isWin ? (VST + (size_t)bb * 256 * 4096) : (VT + (size_t)bb * 256 * 2048);
    const int VS = isWin ? 4096 : 2048;
    const int tokwave = (isWin ? rloc : (rloc - 4096)) + wid * 64;
#pragma unroll
    for (int nt = 0; nt < 8; ++nt) {
      const int cur = nt & 1, nxt = cur ^ 1;
      if (nt + 1 < 8) {
        const u16* bp = bcol0 + (size_t)(nt + 1) * 16 * 256;
#pragma unroll
        for (int ks = 0; ks < 8; ++ks) bq[nxt][ks] = ld16(bp + ks * 32);
      }
      f32x4 acc[4] = {{0.f,0.f,0.f,0.f},{0.f,0.f,0.f,0.f},{0.f,0.f,0.f,0.f},{0.f,0.f,0.f,0.f}};
#pragma unroll
      for (int ks = 0; ks < 8; ++ks) {
#pragma unroll
        for (int mt = 0; mt < 4; ++mt)
          acc[mt] = __builtin_amdgcn_mfma_f32_16x16x32_bf16(bq[cur][ks], a[mt][ks], acc[mt], 0, 0, 0);
      }
      float4 bv4 = *reinterpret_cast<const float4*>(bias + n0 + nt * 16 + kg * 4);
      const float* bvp = (const float*)&bv4;
#pragma unroll
      for (int mt = 0; mt < 4; ++mt)
#pragma unroll
        for (int i = 0; i < 4; ++i) {
          int c = (nt & 3) * 16 + kg * 4 + i;   // local col 0..63 within half
          S[c * 72 + mt * 16 + lr] = f2b(acc[mt][i] + bvp[i]);
        }
      if ((nt & 3) == 3) {
        const int colb = (by - 4) * 128 + (nt - 3) * 16;   // V col base of this half
#pragma unroll
        for (int p = 0; p < 4; ++p) {
#pragma unroll
          for (int half = 0; half < 2; ++half) {
            bf16x8 v = *reinterpret_cast<const bf16x8*>(&S[(p * 16 + lr) * 72 + half * 32 + kg * 8]);
            *reinterpret_cast<bf16x8*>(
                Vb + (size_t)(colb + p * 16 + lr) * VS + tokwave + half * 32 + kg * 8) = v;
          }
        }
      }
    }
  }
}

// ---------------- self-attn per-qt helper: max-free row-softmax, normalized P -> LDS ----------------
__device__ __forceinline__ void selfQT(
    int qt, bf16x8 qfq, const bf16x8 (&kf)[4],
    const u16* __restrict__ BiasC, int h, int lane, int lr, int kg, u16* P)
{
  f32x4 st[4];
#pragma unroll
  for (int kt = 0; kt < 4; ++kt) {
    f32x4 z = {0.f,0.f,0.f,0.f};
    st[kt] = __builtin_amdgcn_mfma_f32_16x16x32_bf16(kf[kt], qfq, z, 0, 0, 0);
  }
  const float c0 = INV_SHD;   // Q pre-scaled by INV_SHD*LOG2E in kQKV
  float lsum = 0.f;
#pragma unroll
  for (int kt = 0; kt < 4; ++kt) {
    ushort4 bv = *reinterpret_cast<const ushort4*>(
        BiasC + (size_t)((h * 16 + qt * 4 + kt) * 64 + lane) * 4);
    st[kt][0] = exp2f(st[kt][0] * c0 + b2f(bv.x));
    st[kt][1] = exp2f(st[kt][1] * c0 + b2f(bv.y));
    st[kt][2] = exp2f(st[kt][2] * c0 + b2f(bv.z));
    st[kt][3] = exp2f(st[kt][3] * c0 + b2f(bv.w));
    lsum += st[kt][0] + st[kt][1] + st[kt][2] + st[kt][3];
  }
  lsum = pl16add(lsum);
  lsum = pl32add(lsum);
  float inv = 1.f / lsum;
#pragma unroll
  for (int kt = 0; kt < 4; ++kt) {
    u32 w0 = cvtpk(st[kt][0] * inv, st[kt][1] * inv);
    u32 w1 = cvtpk(st[kt][2] * inv, st[kt][3] * inv);
    *reinterpret_cast<uint2*>(&P[lr * 72 + kt * 16 + kg * 4]) = make_uint2(w0, w1);
  }
}

// ---------------- cross attention helpers (max-free online accumulation) ----------------
__device__ __forceinline__ void cload(
    const u16* __restrict__ kbase, const u16* __restrict__ vbase, int kc0, int lr, int kg,
    bf16x8 (&kf)[4], bf16x8 (&vf)[4])
{
#pragma unroll
  for (int kt = 0; kt < 4; ++kt)
    kf[kt] = ld16(kbase + (size_t)(kc0 + kt * 16 + lr) * 512);
#pragma unroll
  for (int ks = 0; ks < 2; ++ks) {
    vf[ks]     = ld16(vbase + (size_t)lr * 2048 + kc0 + ks * 32 + kg * 8);
    vf[2 + ks] = ld16(vbase + (size_t)(16 + lr) * 2048 + kc0 + ks * 32 + kg * 8);
  }
}

__device__ __forceinline__ void cstep(
    const bf16x8 (&kf)[4], const bf16x8 (&vf)[4], bf16x8 qf,
    u16* P, int lr, int kg, f32x4& o0, f32x4& o1, float& l)
{
  f32x4 st[4];
#pragma unroll
  for (int kt = 0; kt < 4; ++kt) {
    f32x4 z = {0.f,0.f,0.f,0.f};
    st[kt] = __builtin_amdgcn_mfma_f32_16x16x32_bf16(kf[kt], qf, z, 0, 0, 0);
  }
  float lsum = 0.f;
#pragma unroll
  for (int kt = 0; kt < 4; ++kt) {
    st[kt][0] = exp2f(st[kt][0]);
    st[kt][1] = exp2f(st[kt][1]);
    st[kt][2] = exp2f(st[kt][2]);
    st[kt][3] = exp2f(st[kt][3]);
    lsum += st[kt][0] + st[kt][1] + st[kt][2] + st[kt][3];
  }
  lsum = pl16add(lsum);
  l += pl32add(lsum);
#pragma unroll
  for (int kt = 0; kt < 4; ++kt) {
    u32 w0 = cvtpk(st[kt][0], st[kt][1]);
    u32 w1 = cvtpk(st[kt][2], st[kt][3]);
    *reinterpret_cast<uint2*>(&P[lr * 72 + kt * 16 + kg * 4]) = make_uint2(w0, w1);
  }
#pragma unroll
  for (int ks = 0; ks < 2; ++ks) {
    bf16x8 pf = ld16(P + lr * 72 + ks * 32 + kg * 8);
    o0 = __builtin_amdgcn_mfma_f32_16x16x32_bf16(pf, vf[ks],     o0, 0, 0, 0);
    o1 = __builtin_amdgcn_mfma_f32_16x16x32_bf16(pf, vf[2 + ks], o1, 0, 0, 0);
  }
}

// ---------------- fused attention: blocks [0,512) = cross (4 q-tiles/wave, KV-split=2),
// [512,1536) = self.  LDS 36 KB/block.
__global__ __launch_bounds__(256, 3) void kAttn(
    const u16* __restrict__ qk, const u16* __restrict__ BiasC,
    const u16* __restrict__ VST, const u16* __restrict__ VT,
    u16* __restrict__ X, u16* __restrict__ Opart, float* __restrict__ L)
{
  __shared__ u16 Pl[4][4608];   // 4 P-buffers of 1152 per wave
  const int tid = threadIdx.x;
  const int lane = tid & 63, wid = tid >> 6;
  const int lr = lane & 15, kg = lane >> 4;
  const int bx = blockIdx.x;

  if (bx < 512) {
    // cross: wave owns 4 q-tiles (64 q rows) sharing each K/V load
    const int bh = bx & 63, b = bh >> 3, h = bh & 7;
    const int qy = (bx >> 6) & 3, s = bx >> 8;    // s in {0,1}
    const int qw = qy * 256 + wid * 64;           // wave's q base
    const size_t qrow0 = (size_t)b * 6144 + 5120;
    const size_t krow0 = (size_t)b * 6144 + 4096;
    const u16* kbase = qk + ((s ? qrow0 : krow0) * 512) + 256 + h * 32 + kg * 8;
    const u16* vbase = VT + (size_t)bh * 32 * 2048 + s * 1024;
    u16* P = Pl[wid];

    bf16x8 qf[4];
#pragma unroll
    for (int t = 0; t < 4; ++t)
      qf[t] = ld16(qk + (qrow0 + qw + t * 16 + lr) * 512 + h * 32 + kg * 8);

    f32x4 o[4][2] = {};
    float l[4] = {0.f, 0.f, 0.f, 0.f};

#pragma unroll 1
    for (int ck = 0; ck < 16; ++ck) {
      bf16x8 kf[4], vf[4];
      cload(kbase, vbase, ck * 64, lr, kg, kf, vf);
      cstep(kf, vf, qf[0], P,        lr, kg, o[0][0], o[0][1], l[0]);
      cstep(kf, vf, qf[1], P + 1152, lr, kg, o[1][0], o[1][1], l[1]);
      cstep(kf, vf, qf[2], P + 2304, lr, kg, o[2][0], o[2][1], l[2]);
      cstep(kf, vf, qf[3], P + 3456, lr, kg, o[3][0], o[3][1], l[3]);
    }

    const size_t rowb = (size_t)(s * 64 + bh) * 1024;
#pragma unroll
    for (int t = 0; t < 4; ++t) {
#pragma unroll
      for (int i = 0; i < 4; ++i) {
        int qa = qw + t * 16 + kg * 4 + i;
        Opart[(rowb + qa) * 32 + lr]      = f2b(o[t][0][i]);
        Opart[(rowb + qa) * 32 + 16 + lr] = f2b(o[t][1][i]);
      }
    }
    if (kg == 0) {
#pragma unroll
      for (int t = 0; t < 4; ++t)
        L[rowb + qw + t * 16 + lr] = l[t];
    }
  } else {
    const int bid = bx - 512;
    const int w = bid >> 1;
    const int h = (bid & 1) * 4 + wid;
    const int b = w >> 6, wz = w & 63;
    const int wy = wz >> 3, wx = wz & 7;
    const size_t tokbase = (size_t)b * 6144 + wy * 512 + wx * 8;
    const size_t xbase   = (size_t)b * 5120 + wy * 512 + wx * 8;
    u16* P = Pl[wid];

    bf16x8 qf[4], kf[4];
#pragma unroll
    for (int t4 = 0; t4 < 4; ++t4) {
      int t = t4 * 16 + lr;
      size_t row = tokbase + (t >> 3) * 64 + (t & 7);
      const u16* p = qk + row * 512 + h * 32 + kg * 8;
      qf[t4] = ld16(p);
      kf[t4] = ld16(p + 256);
    }
    bf16x8 vf[2][2];
#pragma unroll
    for (int dt = 0; dt < 2; ++dt)
#pragma unroll
      for (int ks = 0; ks < 2; ++ks)
        vf[dt][ks] = ld16(VST + ((size_t)(b * 8 + h) * 32 + dt * 16 + lr) * 4096
                          + (wy * 8 + ks * 4 + kg) * 64 + wx * 8);

    f32x4 o[4][2] = {};
#pragma unroll
    for (int qt = 0; qt < 4; ++qt) {
      selfQT(qt, qf[qt], kf, BiasC, h, lane, lr, kg, P);
#pragma unroll
      for (int ks = 0; ks < 2; ++ks) {
        bf16x8 pf = ld16(P + lr * 72 + ks * 32 + kg * 8);
        o[qt][0] = __builtin_amdgcn_mfma_f32_16x16x32_bf16(pf, vf[0][ks], o[qt][0], 0, 0, 0);
        o[qt][1] = __builtin_amdgcn_mfma_f32_16x16x32_bf16(pf, vf[1][ks], o[qt][1], 0, 0, 0);
      }
    }
#pragma unroll
    for (int qt = 0; qt < 4; ++qt)
#pragma unroll
      for (int i = 0; i < 4; ++i) {
        int t = qt * 16 + kg * 4 + i;
        size_t xrow = xbase + (t >> 3) * 64 + (t & 7);
#pragma unroll
        for (int dt = 0; dt < 2; ++dt)
          X[xrow * 256 + h * 32 + dt * 16 + lr] = f2b(o[qt][dt][i]);
      }
  }
}

// ---------------- combine the 2 KV-splits (m==0: pure sum) ----------------
__global__ __launch_bounds__(256) void kComb(
    const u16* __restrict__ Opart, const float* __restrict__ L, u16* __restrict__ X)
{
  int gid = blockIdx.x * 256 + threadIdx.x;   // 262144
  int row = gid >> 2;                         // bh*1024 + q  (65536 rows)
  int dp = (gid & 3) * 8;
  int bh = row >> 10, q = row & 1023;
  int b = bh >> 3, h = bh & 7;
  float lsum = L[row] + L[65536 + row];
  float inv = 1.f / lsum;
  float acc[8] = {0.f,0.f,0.f,0.f,0.f,0.f,0.f,0.f};
#pragma unroll
  for (int s = 0; s < 2; ++s) {
    U8 a;
    a.v = ld16(Opart + ((size_t)(s * 65536 + row) * 32 + dp));
#pragma unroll
    for (int j = 0; j < 8; ++j) acc[j] += b2f(a.s[j]);
  }
  U8 r;
#pragma unroll
  for (int j = 0; j < 8; ++j) r.s[j] = f2b(acc[j] * inv);
  size_t xrow = (size_t)b * 5120 + 4096 + q;
  *reinterpret_cast<bf16x8*>(X + xrow * 256 + h * 32 + dp) = r.v;
}

// ---------------- output projection: [40960,256] @ [256,256] -> f32 out ----------------
// 4 m-tiles per wave + B double-buffer. Grid (160,2).
__global__ __launch_bounds__(256, 3) void kProj(
    const u16* __restrict__ Xin, const u16* __restrict__ WT, const float* __restrict__ bias,
    float* __restrict__ out)
{
  const int tid = threadIdx.x;
  const int lane = tid & 63, wid = tid >> 6;
  const int lr = lane & 15, kg = lane >> 4;
  const int m0 = blockIdx.x * 256 + wid * 64;
  const int n0 = blockIdx.y * 128;
  bf16x8 a[4][8];
#pragma unroll
  for (int mt = 0; mt < 4; ++mt) {
    const u16* src = Xin + (size_t)(m0 + mt * 16 + lr) * 256 + kg * 8;
#pragma unroll
    for (int ks = 0; ks < 8; ++ks) a[mt][ks] = ld16(src + ks * 32);
  }
  const u16* bcol0 = WT + (size_t)(n0 + lr) * 256 + kg * 8;
  bf16x8 bq[2][8];
#pragma unroll
  for (int ks = 0; ks < 8; ++ks) bq[0][ks] = ld16(bcol0 + ks * 32);
#pragma unroll
  for (int nt = 0; nt < 8; ++nt) {
    const int cur = nt & 1, nxt = cur ^ 1;
    if (nt + 1 < 8) {
      const u16* bp = bcol0 + (size_t)(nt + 1) * 16 * 256;
#pragma unroll
      for (int ks = 0; ks < 8; ++ks) bq[nxt][ks] = ld16(bp + ks * 32);
    }
    f32x4 acc[4] = {{0.f,0.f,0.f,0.f},{0.f,0.f,0.f,0.f},{0.f,0.f,0.f,0.f},{0.f,0.f,0.f,0.f}};
#pragma unroll
    for (int ks = 0; ks < 8; ++ks) {
#pragma unroll
      for (int mt = 0; mt < 4; ++mt)
        acc[mt] = __builtin_amdgcn_mfma_f32_16x16x32_bf16(a[mt][ks], bq[cur][ks], acc[mt], 0, 0, 0);
    }
    const int n = n0 + nt * 16;
    float bv = bias[n + lr];
#pragma unroll
    for (int mt = 0; mt < 4; ++mt)
#pragma unroll
      for (int i = 0; i < 4; ++i) {
        int r0 = m0 + mt * 16 + kg * 4 + i;
        out[(size_t)r0 * 256 + n + lr] = acc[mt][i] + bv;
      }
  }
}

extern "C" void kernel_launch(void* const* d_in, const int* in_sizes, int n_in,
                              void* d_out, int out_size, void* d_ws, size_t ws_size,
                              hipStream_t stream)
{
  const float* xs1   = (const float*)d_in[0];
  const float* xs2   = (const float*)d_in[1];
  const float* xq    = (const float*)d_in[2];
  const float* Wqkv  = (const float*)d_in[3];
  const float* bqkv  = (const float*)d_in[4];
  const float* Wproj = (const float*)d_in[5];
  const float* bproj = (const float*)d_in[6];
  const float* tbl   = (const float*)d_in[7];

  u16* ws  = (u16*)d_ws;
  u16* qk  = ws;                 // 49152*512 = 25165824 elems (bf16)
  u16* X   = qk + 25165824;      // 40960*256 = 10485760
  u16* WTq = X + 10485760;       // 768*256   =   196608
  u16* WTp = WTq + 196608;       // 256*256   =    65536
  u16* VT  = WTp + 65536;        // 8*8*32*2048 = 4194304
  u16* VST = VT + 4194304;       // 8*8*32*4096 = 8388608

  // scratch inside d_out (40 MiB, fully overwritten by kProj at the end).
  // Liveness aliasing: Abf (written kPrep, read kQKV, then DEAD) shares the
  // region with Opart (first written in kAttn, read kComb).
  u16*   BiasC = (u16*)d_out;                               // @0       (0.25 MB)
  float* L     = (float*)((char*)d_out + 262144);           // @0.25MB  (1 MB; 2x65536 f32 used)
  u16*   Abf   = (u16*)((char*)d_out + 1310720);            // @1.25MB  (24 MB, dead after kQKV)
  u16*   Opart = (u16*)((char*)d_out + 1310720);            // @1.25MB  (8 MB, aliases Abf)

  kPrep<<<7200, 256, 0, stream>>>(xs1, xs2, xq, Wqkv, Wproj, tbl, Abf, WTq, WTp, BiasC);
  kQKV<<<dim3(192, 6), 256, 0, stream>>>(Abf, WTq, bqkv, qk, VT, VST);
  kAttn<<<1536, 256, 0, stream>>>(qk, BiasC, VST, VT, X, Opart, L);
  kComb<<<1024, 256, 0, stream>>>(Opart, L, X);
  kProj<<<dim3(160, 2), 256, 0, stream>>>(X, WTp, bproj, (float*)d_out);
}

// Round 24
// 189.240 us; speedup vs baseline: 1.0050x; 1.0050x over previous
//
#include <hip/hip_runtime.h>
#include <hip/hip_bf16.h>

typedef unsigned short u16;
typedef unsigned int u32;
typedef __attribute__((ext_vector_type(8))) __bf16 bf16x8;
typedef __attribute__((ext_vector_type(4))) float f32x4;

#define INV_HD  0.03125f
#define INV_SHD 0.17677669529663687f
#define LOG2E   1.4426950408889634f

__device__ __forceinline__ float b2f(u16 u) {
  union { u32 i; float f; } v; v.i = ((u32)u) << 16; return v.f;
}
__device__ __forceinline__ u16 f2b(float f) {
  union { float f; u32 i; } v; v.f = f;
  u32 x = v.i;
  return (u16)((x + 0x7fffu + ((x >> 16) & 1u)) >> 16);
}
__device__ __forceinline__ bf16x8 ld16(const u16* p) {
  return *reinterpret_cast<const bf16x8*>(p);
}
union U8 { bf16x8 v; u16 s[8]; };
__device__ __forceinline__ u32 cvtpk(float a, float b) {
  u32 r;
  asm("v_cvt_pk_bf16_f32 %0, %1, %2" : "=v"(r) : "v"(a), "v"(b));
  return r;
}
// lane^32 / lane^16 sum reduce via permlane swaps (VALU, no LDS latency)
__device__ __forceinline__ float pl32add(float x) {
  union { float f; u32 u; } c; c.f = x;
  auto r = __builtin_amdgcn_permlane32_swap(c.u, c.u, false, false);
  union { u32 u; float f; } a, b; a.u = r[0]; b.u = r[1];
  return a.f + b.f;
}
__device__ __forceinline__ float pl16add(float x) {
#if __has_builtin(__builtin_amdgcn_permlane16_swap)
  union { float f; u32 u; } c; c.f = x;
  auto r = __builtin_amdgcn_permlane16_swap(c.u, c.u, false, false);
  union { u32 u; float f; } a, b; a.u = r[0]; b.u = r[1];
  return a.f + b.f;
#else
  return x + __shfl_xor(x, 16, 64);
#endif
}

// ---------------- fused prep: A-convert + 2 weight transposes + bias expand ----------------
__global__ __launch_bounds__(256) void kPrep(
    const float* __restrict__ xs1, const float* __restrict__ xs2, const float* __restrict__ xq,
    const float* __restrict__ Wqkv, const float* __restrict__ Wproj, const float* __restrict__ tblg,
    u16* __restrict__ Abf, u16* __restrict__ WTq, u16* __restrict__ WTp, u16* __restrict__ BiasC)
{
  const int bx = blockIdx.x, tid = threadIdx.x;
  if (bx < 6144) {
    int t = bx * 256 + tid;
    int row = t >> 5, c8 = (t & 31) * 8;
    int b = row / 6144, r = row - b * 6144;
    const float* src;
    if (r < 4096)      src = xs1 + ((size_t)b * 4096 + r) * 256;
    else if (r < 5120) src = xs2 + ((size_t)b * 1024 + (r - 4096)) * 256;
    else               src = xq  + ((size_t)b * 1024 + (r - 5120)) * 256;
    U8 u;
#pragma unroll
    for (int j = 0; j < 8; ++j) u.s[j] = f2b(src[c8 + j]);
    *reinterpret_cast<bf16x8*>(Abf + (size_t)row * 256 + c8) = u.v;
  } else if (bx < 6912) {
    int i = (bx - 6144) * 256 + tid;       // 196608
    int n = i >> 8, k = i & 255;
    WTq[i] = f2b(Wqkv[(size_t)k * 768 + n]);
  } else if (bx < 7168) {
    int i = (bx - 6912) * 256 + tid;       // 65536
    int n = i >> 8, k = i & 255;
    WTp[i] = f2b(Wproj[(size_t)k * 256 + n]);
  } else {
    int gid = (bx - 7168) * 256 + tid;     // 8192
    int lane = gid & 63, t = gid >> 6;
    int h = t >> 4, qt = (t >> 2) & 3, kt = t & 3;
    int lr = lane & 15, kg = lane >> 4;
    int q = qt * 16 + lr;
    int qi = q >> 3, qj = q & 7;
    ushort4 out;
#pragma unroll
    for (int i = 0; i < 4; ++i) {
      int key = kt * 16 + kg * 4 + i;
      int ki = key >> 3, kj = key & 7;
      int idx = (qi - ki + 7) * 15 + (qj - kj + 7);
      ((u16*)&out)[i] = f2b(tblg[idx * 8 + h] * (INV_SHD * LOG2E));
    }
    *reinterpret_cast<ushort4*>(BiasC + (size_t)(t * 64 + lane) * 4) = out;
  }
}

// ---------------- QKV GEMM: bf16 A [49152,256] @ [256,768], barrier-free ----------------
// 4 m-tiles per wave; LDS staging 9KB/wave (36KB/block): stage 4 nt-iters, flush, repeat.
__global__ __launch_bounds__(256, 2) void kQKV(
    const u16* __restrict__ Abf,
    const u16* __restrict__ WT, const float* __restrict__ bias,
    u16* __restrict__ qk, u16* __restrict__ VT, u16* __restrict__ VST)
{
  __shared__ u16 St[4][4608];   // 9 KB per wave, 36 KB per block
  const int tid = threadIdx.x;
  const int lane = tid & 63, wid = tid >> 6;
  const int lr = lane & 15, kg = lane >> 4;
  const int m0 = blockIdx.x * 256 + wid * 64;
  const int by = blockIdx.y;
  const int m0blk = blockIdx.x * 256;
  const int bb = m0blk / 6144, rloc = m0blk - bb * 6144;
  u16* S = St[wid];

  bf16x8 a[4][8];
#pragma unroll
  for (int mt = 0; mt < 4; ++mt) {
    const u16* asrc = Abf + (size_t)(m0 + mt * 16 + lr) * 256 + kg * 8;
#pragma unroll
    for (int ks = 0; ks < 8; ++ks) a[mt][ks] = ld16(asrc + ks * 32);
  }

  const int n0 = (by < 4) ? by * 128 : 512 + (by - 4) * 128;
  const u16* bcol0 = WT + (size_t)(n0 + lr) * 256 + kg * 8;

  bf16x8 bq[2][8];
#pragma unroll
  for (int ks = 0; ks < 8; ++ks) bq[0][ks] = ld16(bcol0 + ks * 32);   // nt=0

  if (by < 4) {
    const float qsc = (by < 2) ? (INV_SHD * LOG2E) : 1.f;
#pragma unroll
    for (int nt = 0; nt < 8; ++nt) {
      const int cur = nt & 1, nxt = cur ^ 1;
      if (nt + 1 < 8) {
        const u16* bp = bcol0 + (size_t)(nt + 1) * 16 * 256;
#pragma unroll
        for (int ks = 0; ks < 8; ++ks) bq[nxt][ks] = ld16(bp + ks * 32);
      }
      f32x4 acc[4] = {{0.f,0.f,0.f,0.f},{0.f,0.f,0.f,0.f},{0.f,0.f,0.f,0.f},{0.f,0.f,0.f,0.f}};
#pragma unroll
      for (int ks = 0; ks < 8; ++ks) {
#pragma unroll
        for (int mt = 0; mt < 4; ++mt)
          acc[mt] = __builtin_amdgcn_mfma_f32_16x16x32_bf16(a[mt][ks], bq[cur][ks], acc[mt], 0, 0, 0);
      }
      float bv = bias[n0 + nt * 16 + lr];
      const int tc = (nt & 3) * 16;
#pragma unroll
      for (int mt = 0; mt < 4; ++mt)
#pragma unroll
        for (int i = 0; i < 4; ++i)
          S[(mt * 16 + kg * 4 + i) * 72 + tc + lr] = f2b((acc[mt][i] + bv) * qsc);
      if ((nt & 3) == 3) {
        const int cb = (nt - 3) * 16;   // 0 or 64
#pragma unroll
        for (int p = 0; p < 8; ++p) {
          int row = p * 8 + (lane >> 3), col8 = (lane & 7) * 8;
          bf16x8 v = *reinterpret_cast<const bf16x8*>(&S[row * 72 + col8]);
          *reinterpret_cast<bf16x8*>(qk + (size_t)(m0 + row) * 512 + n0 + cb + col8) = v;
        }
      }
    }
  } else {
    const bool isWin = (rloc < 4096);
    u16* Vb = isWin ? (VST + (size_t)bb * 256 * 4096) : (VT + (size_t)bb * 256 * 2048);
    const int VS = isWin ? 4096 : 2048;
    const int tokwave = (isWin ? rloc : (rloc - 4096)) + wid * 64;
#pragma unroll
    for (int nt = 0; nt < 8; ++nt) {
      const int cur = nt & 1, nxt = cur ^ 1;
      if (nt + 1 < 8) {
        const u16* bp = bcol0 + (size_t)(nt + 1) * 16 * 256;
#pragma unroll
        for (int ks = 0; ks < 8; ++ks) bq[nxt][ks] = ld16(bp + ks * 32);
      }
      f32x4 acc[4] = {{0.f,0.f,0.f,0.f},{0.f,0.f,0.f,0.f},{0.f,0.f,0.f,0.f},{0.f,0.f,0.f,0.f}};
#pragma unroll
      for (int ks = 0; ks < 8; ++ks) {
#pragma unroll
        for (int mt = 0; mt < 4; ++mt)
          acc[mt] = __builtin_amdgcn_mfma_f32_16x16x32_bf16(bq[cur][ks], a[mt][ks], acc[mt], 0, 0, 0);
      }
      float4 bv4 = *reinterpret_cast<const float4*>(bias + n0 + nt * 16 + kg * 4);
      const float* bvp = (const float*)&bv4;
#pragma unroll
      for (int mt = 0; mt < 4; ++mt)
#pragma unroll
        for (int i = 0; i < 4; ++i) {
          int c = (nt & 3) * 16 + kg * 4 + i;   // local col 0..63 within half
          S[c * 72 + mt * 16 + lr] = f2b(acc[mt][i] + bvp[i]);
        }
      if ((nt & 3) == 3) {
        const int colb = (by - 4) * 128 + (nt - 3) * 16;   // V col base of this half
#pragma unroll
        for (int p = 0; p < 4; ++p) {
#pragma unroll
          for (int half = 0; half < 2; ++half) {
            bf16x8 v = *reinterpret_cast<const bf16x8*>(&S[(p * 16 + lr) * 72 + half * 32 + kg * 8]);
            *reinterpret_cast<bf16x8*>(
                Vb + (size_t)(colb + p * 16 + lr) * VS + tokwave + half * 32 + kg * 8) = v;
          }
        }
      }
    }
  }
}

// ---------------- self-attn per-qt helper: max-free row-softmax, normalized P -> LDS ----------------
__device__ __forceinline__ void selfQT(
    int qt, bf16x8 qfq, const bf16x8 (&kf)[4],
    const u16* __restrict__ BiasC, int h, int lane, int lr, int kg, u16* P)
{
  f32x4 st[4];
#pragma unroll
  for (int kt = 0; kt < 4; ++kt) {
    f32x4 z = {0.f,0.f,0.f,0.f};
    st[kt] = __builtin_amdgcn_mfma_f32_16x16x32_bf16(kf[kt], qfq, z, 0, 0, 0);
  }
  const float c0 = INV_SHD;   // Q pre-scaled by INV_SHD*LOG2E in kQKV
  float lsum = 0.f;
#pragma unroll
  for (int kt = 0; kt < 4; ++kt) {
    ushort4 bv = *reinterpret_cast<const ushort4*>(
        BiasC + (size_t)((h * 16 + qt * 4 + kt) * 64 + lane) * 4);
    st[kt][0] = exp2f(st[kt][0] * c0 + b2f(bv.x));
    st[kt][1] = exp2f(st[kt][1] * c0 + b2f(bv.y));
    st[kt][2] = exp2f(st[kt][2] * c0 + b2f(bv.z));
    st[kt][3] = exp2f(st[kt][3] * c0 + b2f(bv.w));
    lsum += st[kt][0] + st[kt][1] + st[kt][2] + st[kt][3];
  }
  lsum = pl16add(lsum);
  lsum = pl32add(lsum);
  float inv = 1.f / lsum;
#pragma unroll
  for (int kt = 0; kt < 4; ++kt) {
    u32 w0 = cvtpk(st[kt][0] * inv, st[kt][1] * inv);
    u32 w1 = cvtpk(st[kt][2] * inv, st[kt][3] * inv);
    *reinterpret_cast<uint2*>(&P[lr * 72 + kt * 16 + kg * 4]) = make_uint2(w0, w1);
  }
}

// ---------------- cross attention helpers (max-free online accumulation) ----------------
__device__ __forceinline__ void cload(
    const u16* __restrict__ kbase, const u16* __restrict__ vbase, int kc0, int lr, int kg,
    bf16x8 (&kf)[4], bf16x8 (&vf)[4])
{
#pragma unroll
  for (int kt = 0; kt < 4; ++kt)
    kf[kt] = ld16(kbase + (size_t)(kc0 + kt * 16 + lr) * 512);
#pragma unroll
  for (int ks = 0; ks < 2; ++ks) {
    vf[ks]     = ld16(vbase + (size_t)lr * 2048 + kc0 + ks * 32 + kg * 8);
    vf[2 + ks] = ld16(vbase + (size_t)(16 + lr) * 2048 + kc0 + ks * 32 + kg * 8);
  }
}

__device__ __forceinline__ void cstep(
    const bf16x8 (&kf)[4], const bf16x8 (&vf)[4], bf16x8 qf,
    u16* P, int lr, int kg, f32x4& o0, f32x4& o1, float& l)
{
  f32x4 st[4];
#pragma unroll
  for (int kt = 0; kt < 4; ++kt) {
    f32x4 z = {0.f,0.f,0.f,0.f};
    st[kt] = __builtin_amdgcn_mfma_f32_16x16x32_bf16(kf[kt], qf, z, 0, 0, 0);
  }
  float lsum = 0.f;
#pragma unroll
  for (int kt = 0; kt < 4; ++kt) {
    st[kt][0] = exp2f(st[kt][0]);
    st[kt][1] = exp2f(st[kt][1]);
    st[kt][2] = exp2f(st[kt][2]);
    st[kt][3] = exp2f(st[kt][3]);
    lsum += st[kt][0] + st[kt][1] + st[kt][2] + st[kt][3];
  }
  lsum = pl16add(lsum);
  l += pl32add(lsum);
#pragma unroll
  for (int kt = 0; kt < 4; ++kt) {
    u32 w0 = cvtpk(st[kt][0], st[kt][1]);
    u32 w1 = cvtpk(st[kt][2], st[kt][3]);
    *reinterpret_cast<uint2*>(&P[lr * 72 + kt * 16 + kg * 4]) = make_uint2(w0, w1);
  }
#pragma unroll
  for (int ks = 0; ks < 2; ++ks) {
    bf16x8 pf = ld16(P + lr * 72 + ks * 32 + kg * 8);
    o0 = __builtin_amdgcn_mfma_f32_16x16x32_bf16(pf, vf[ks],     o0, 0, 0, 0);
    o1 = __builtin_amdgcn_mfma_f32_16x16x32_bf16(pf, vf[2 + ks], o1, 0, 0, 0);
  }
}

// ---------------- fused attention: blocks [0,512) = cross (4 q-tiles/wave, KV-split=2),
// [512,1536) = self.  LDS 36 KB/block.  (256,2): allocator may take ~128 VGPR so all
// kf/vf loads stay in flight (r23 profile showed 64-VGPR squeeze serializing loads).
__global__ __launch_bounds__(256, 2) void kAttn(
    const u16* __restrict__ qk, const u16* __restrict__ BiasC,
    const u16* __restrict__ VST, const u16* __restrict__ VT,
    u16* __restrict__ X, u16* __restrict__ Opart, float* __restrict__ L)
{
  __shared__ u16 Pl[4][4608];   // 4 P-buffers of 1152 per wave
  const int tid = threadIdx.x;
  const int lane = tid & 63, wid = tid >> 6;
  const int lr = lane & 15, kg = lane >> 4;
  const int bx = blockIdx.x;

  if (bx < 512) {
    // cross: wave owns 4 q-tiles (64 q rows) sharing each K/V load
    const int bh = bx & 63, b = bh >> 3, h = bh & 7;
    const int qy = (bx >> 6) & 3, s = bx >> 8;    // s in {0,1}
    const int qw = qy * 256 + wid * 64;           // wave's q base
    const size_t qrow0 = (size_t)b * 6144 + 5120;
    const size_t krow0 = (size_t)b * 6144 + 4096;
    const u16* kbase = qk + ((s ? qrow0 : krow0) * 512) + 256 + h * 32 + kg * 8;
    const u16* vbase = VT + (size_t)bh * 32 * 2048 + s * 1024;
    u16* P = Pl[wid];

    bf16x8 qf[4];
#pragma unroll
    for (int t = 0; t < 4; ++t)
      qf[t] = ld16(qk + (qrow0 + qw + t * 16 + lr) * 512 + h * 32 + kg * 8);

    f32x4 o[4][2] = {};
    float l[4] = {0.f, 0.f, 0.f, 0.f};

#pragma unroll 1
    for (int ck = 0; ck < 16; ++ck) {
      bf16x8 kf[4], vf[4];
      cload(kbase, vbase, ck * 64, lr, kg, kf, vf);
      cstep(kf, vf, qf[0], P,        lr, kg, o[0][0], o[0][1], l[0]);
      cstep(kf, vf, qf[1], P + 1152, lr, kg, o[1][0], o[1][1], l[1]);
      cstep(kf, vf, qf[2], P + 2304, lr, kg, o[2][0], o[2][1], l[2]);
      cstep(kf, vf, qf[3], P + 3456, lr, kg, o[3][0], o[3][1], l[3]);
    }

    const size_t rowb = (size_t)(s * 64 + bh) * 1024;
#pragma unroll
    for (int t = 0; t < 4; ++t) {
#pragma unroll
      for (int i = 0; i < 4; ++i) {
        int qa = qw + t * 16 + kg * 4 + i;
        Opart[(rowb + qa) * 32 + lr]      = f2b(o[t][0][i]);
        Opart[(rowb + qa) * 32 + 16 + lr] = f2b(o[t][1][i]);
      }
    }
    if (kg == 0) {
#pragma unroll
      for (int t = 0; t < 4; ++t)
        L[rowb + qw + t * 16 + lr] = l[t];
    }
  } else {
    const int bid = bx - 512;
    const int w = bid >> 1;
    const int h = (bid & 1) * 4 + wid;
    const int b = w >> 6, wz = w & 63;
    const int wy = wz >> 3, wx = wz & 7;
    const size_t tokbase = (size_t)b * 6144 + wy * 512 + wx * 8;
    const size_t xbase   = (size_t)b * 5120 + wy * 512 + wx * 8;
    u16* P = Pl[wid];

    bf16x8 qf[4], kf[4];
#pragma unroll
    for (int t4 = 0; t4 < 4; ++t4) {
      int t = t4 * 16 + lr;
      size_t row = tokbase + (t >> 3) * 64 + (t & 7);
      const u16* p = qk + row * 512 + h * 32 + kg * 8;
      qf[t4] = ld16(p);
      kf[t4] = ld16(p + 256);
    }
    bf16x8 vf[2][2];
#pragma unroll
    for (int dt = 0; dt < 2; ++dt)
#pragma unroll
      for (int ks = 0; ks < 2; ++ks)
        vf[dt][ks] = ld16(VST + ((size_t)(b * 8 + h) * 32 + dt * 16 + lr) * 4096
                          + (wy * 8 + ks * 4 + kg) * 64 + wx * 8);

    f32x4 o[4][2] = {};
#pragma unroll
    for (int qt = 0; qt < 4; ++qt) {
      selfQT(qt, qf[qt], kf, BiasC, h, lane, lr, kg, P);
#pragma unroll
      for (int ks = 0; ks < 2; ++ks) {
        bf16x8 pf = ld16(P + lr * 72 + ks * 32 + kg * 8);
        o[qt][0] = __builtin_amdgcn_mfma_f32_16x16x32_bf16(pf, vf[0][ks], o[qt][0], 0, 0, 0);
        o[qt][1] = __builtin_amdgcn_mfma_f32_16x16x32_bf16(pf, vf[1][ks], o[qt][1], 0, 0, 0);
      }
    }
#pragma unroll
    for (int qt = 0; qt < 4; ++qt)
#pragma unroll
      for (int i = 0; i < 4; ++i) {
        int t = qt * 16 + kg * 4 + i;
        size_t xrow = xbase + (t >> 3) * 64 + (t & 7);
#pragma unroll
        for (int dt = 0; dt < 2; ++dt)
          X[xrow * 256 + h * 32 + dt * 16 + lr] = f2b(o[qt][dt][i]);
      }
  }
}

// ---------------- combine the 2 KV-splits (m==0: pure sum) ----------------
__global__ __launch_bounds__(256) void kComb(
    const u16* __restrict__ Opart, const float* __restrict__ L, u16* __restrict__ X)
{
  int gid = blockIdx.x * 256 + threadIdx.x;   // 262144
  int row = gid >> 2;                         // bh*1024 + q  (65536 rows)
  int dp = (gid & 3) * 8;
  int bh = row >> 10, q = row & 1023;
  int b = bh >> 3, h = bh & 7;
  float lsum = L[row] + L[65536 + row];
  float inv = 1.f / lsum;
  float acc[8] = {0.f,0.f,0.f,0.f,0.f,0.f,0.f,0.f};
#pragma unroll
  for (int s = 0; s < 2; ++s) {
    U8 a;
    a.v = ld16(Opart + ((size_t)(s * 65536 + row) * 32 + dp));
#pragma unroll
    for (int j = 0; j < 8; ++j) acc[j] += b2f(a.s[j]);
  }
  U8 r;
#pragma unroll
  for (int j = 0; j < 8; ++j) r.s[j] = f2b(acc[j] * inv);
  size_t xrow = (size_t)b * 5120 + 4096 + q;
  *reinterpret_cast<bf16x8*>(X + xrow * 256 + h * 32 + dp) = r.v;
}

// ---------------- output projection: [40960,256] @ [256,256] -> f32 out ----------------
// 4 m-tiles per wave + B double-buffer. Grid (160,2).
__global__ __launch_bounds__(256, 3) void kProj(
    const u16* __restrict__ Xin, const u16* __restrict__ WT, const float* __restrict__ bias,
    float* __restrict__ out)
{
  const int tid = threadIdx.x;
  const int lane = tid & 63, wid = tid >> 6;
  const int lr = lane & 15, kg = lane >> 4;
  const int m0 = blockIdx.x * 256 + wid * 64;
  const int n0 = blockIdx.y * 128;
  bf16x8 a[4][8];
#pragma unroll
  for (int mt = 0; mt < 4; ++mt) {
    const u16* src = Xin + (size_t)(m0 + mt * 16 + lr) * 256 + kg * 8;
#pragma unroll
    for (int ks = 0; ks < 8; ++ks) a[mt][ks] = ld16(src + ks * 32);
  }
  const u16* bcol0 = WT + (size_t)(n0 + lr) * 256 + kg * 8;
  bf16x8 bq[2][8];
#pragma unroll
  for (int ks = 0; ks < 8; ++ks) bq[0][ks] = ld16(bcol0 + ks * 32);
#pragma unroll
  for (int nt = 0; nt < 8; ++nt) {
    const int cur = nt & 1, nxt = cur ^ 1;
    if (nt + 1 < 8) {
      const u16* bp = bcol0 + (size_t)(nt + 1) * 16 * 256;
#pragma unroll
      for (int ks = 0; ks < 8; ++ks) bq[nxt][ks] = ld16(bp + ks * 32);
    }
    f32x4 acc[4] = {{0.f,0.f,0.f,0.f},{0.f,0.f,0.f,0.f},{0.f,0.f,0.f,0.f},{0.f,0.f,0.f,0.f}};
#pragma unroll
    for (int ks = 0; ks < 8; ++ks) {
#pragma unroll
      for (int mt = 0; mt < 4; ++mt)
        acc[mt] = __builtin_amdgcn_mfma_f32_16x16x32_bf16(a[mt][ks], bq[cur][ks], acc[mt], 0, 0, 0);
    }
    const int n = n0 + nt * 16;
    float bv = bias[n + lr];
#pragma unroll
    for (int mt = 0; mt < 4; ++mt)
#pragma unroll
      for (int i = 0; i < 4; ++i) {
        int r0 = m0 + mt * 16 + kg * 4 + i;
        out[(size_t)r0 * 256 + n + lr] = acc[mt][i] + bv;
      }
  }
}

extern "C" void kernel_launch(void* const* d_in, const int* in_sizes, int n_in,
                              void* d_out, int out_size, void* d_ws, size_t ws_size,
                              hipStream_t stream)
{
  const float* xs1   = (const float*)d_in[0];
  const float* xs2   = (const float*)d_in[1];
  const float* xq    = (const float*)d_in[2];
  const float* Wqkv  = (const float*)d_in[3];
  const float* bqkv  = (const float*)d_in[4];
  const float* Wproj = (const float*)d_in[5];
  const float* bproj = (const float*)d_in[6];
  const float* tbl   = (const float*)d_in[7];

  u16* ws  = (u16*)d_ws;
  u16* qk  = ws;                 // 49152*512 = 25165824 elems (bf16)
  u16* X   = qk + 25165824;      // 40960*256 = 10485760
  u16* WTq = X + 10485760;       // 768*256   =   196608
  u16* WTp = WTq + 196608;       // 256*256   =    65536
  u16* VT  = WTp + 65536;        // 8*8*32*2048 = 4194304
  u16* VST = VT + 4194304;       // 8*8*32*4096 = 8388608

  // scratch inside d_out (40 MiB, fully overwritten by kProj at the end).
  // Liveness aliasing: Abf (written kPrep, read kQKV, then DEAD) shares the
  // region with Opart (first written in kAttn, read kComb).
  u16*   BiasC = (u16*)d_out;                               // @0       (0.25 MB)
  float* L     = (float*)((char*)d_out + 262144);           // @0.25MB  (1 MB; 2x65536 f32 used)
  u16*   Abf   = (u16*)((char*)d_out + 1310720);            // @1.25MB  (24 MB, dead after kQKV)
  u16*   Opart = (u16*)((char*)d_out + 1310720);            // @1.25MB  (8 MB, aliases Abf)

  kPrep<<<7200, 256, 0, stream>>>(xs1, xs2, xq, Wqkv, Wproj, tbl, Abf, WTq, WTp, BiasC);
  kQKV<<<dim3(192, 6), 256, 0, stream>>>(Abf, WTq, bqkv, qk, VT, VST);
  kAttn<<<1536, 256, 0, stream>>>(qk, BiasC, VST, VT, X, Opart, L);
  kComb<<<1024, 256, 0, stream>>>(Opart, L, X);
  kProj<<<dim3(160, 2), 256, 0, stream>>>(X, WTp, bproj, (float*)d_out);
}